// Round 1
// baseline (970.256 us; speedup 1.0000x reference)
//
#include <hip/hip_runtime.h>

// Problem constants
constexpr int B_ = 2;
constexpr int S_ = 2048;
constexpr int D_ = 1024;
constexpr int H_ = 16;
constexpr int DH_ = 64;
constexpr int M_ = B_ * S_;        // 4096 rows

// ---------------------------------------------------------------------------
// fp32 tiled GEMM: C[M,N] = A[M,K] @ W[K,N] + bias[N]
// 128x128 tile, BK=16, 256 threads, 8x8 register blocking.
// ---------------------------------------------------------------------------
__global__ __launch_bounds__(256)
void gemm_bias_f32(const float* __restrict__ A, const float* __restrict__ W,
                   const float* __restrict__ bias, float* __restrict__ C,
                   int M, int N, int K) {
  constexpr int BM = 128, BN = 128, BK = 16;
  __shared__ float As[BK][BM + 4];   // stored transposed: As[k][m]
  __shared__ float Bs[BK][BN + 4];   // natural: Bs[k][n]

  const int t  = threadIdx.x;
  const int m0 = blockIdx.y * BM;
  const int n0 = blockIdx.x * BN;
  const int tx = t & 15, ty = t >> 4;

  float acc[8][8];
#pragma unroll
  for (int i = 0; i < 8; i++)
#pragma unroll
    for (int j = 0; j < 8; j++) acc[i][j] = 0.f;

  for (int k0 = 0; k0 < K; k0 += BK) {
    // A tile: BM x BK = 512 float4, 2 per thread; store transposed
#pragma unroll
    for (int i = 0; i < 2; i++) {
      int s = t + i * 256;
      int row = s >> 2, c4 = s & 3;
      float4 v = *reinterpret_cast<const float4*>(A + (size_t)(m0 + row) * K + (k0 + c4 * 4));
      As[c4 * 4 + 0][row] = v.x;
      As[c4 * 4 + 1][row] = v.y;
      As[c4 * 4 + 2][row] = v.z;
      As[c4 * 4 + 3][row] = v.w;
    }
    // B tile: BK x BN = 512 float4, 2 per thread
#pragma unroll
    for (int i = 0; i < 2; i++) {
      int s = t + i * 256;
      int row = s >> 5, c4 = s & 31;
      *reinterpret_cast<float4*>(&Bs[row][c4 * 4]) =
          *reinterpret_cast<const float4*>(W + (size_t)(k0 + row) * N + (n0 + c4 * 4));
    }
    __syncthreads();
#pragma unroll
    for (int k = 0; k < BK; k++) {
      float a[8], bb[8];
#pragma unroll
      for (int i = 0; i < 8; i++) a[i] = As[k][ty * 8 + i];
#pragma unroll
      for (int j = 0; j < 8; j++) bb[j] = Bs[k][tx * 8 + j];
#pragma unroll
      for (int i = 0; i < 8; i++)
#pragma unroll
        for (int j = 0; j < 8; j++)
          acc[i][j] = fmaf(a[i], bb[j], acc[i][j]);
    }
    __syncthreads();
  }

#pragma unroll
  for (int i = 0; i < 8; i++) {
    size_t m = (size_t)(m0 + ty * 8 + i);
#pragma unroll
    for (int j = 0; j < 8; j += 4) {
      int n = n0 + tx * 8 + j;
      float4 v;
      v.x = acc[i][j + 0] + bias[n + 0];
      v.y = acc[i][j + 1] + bias[n + 1];
      v.z = acc[i][j + 2] + bias[n + 2];
      v.w = acc[i][j + 3] + bias[n + 3];
      *reinterpret_cast<float4*>(C + m * N + n) = v;
    }
  }
}

// ---------------------------------------------------------------------------
// fp32 flash attention.
// qkv layout: [B*S, 3*D] rows; Q at col h*64, K at D + h*64, V at 2D + h*64.
// Grid: (S/64, H, B). Block: 256 threads = 16x16 (tx, ty).
// Each block: 64 q-rows x all 2048 kv, online softmax.
// Per thread: 4x4 score block (rows ty*4+i, cols kk=tx*4+j) and
//             4x4 output block (rows ty*4+i, dh cols tx*4+j).
// Row-group = 16 lanes sharing ty -> width-16 shfl reductions (in-wave).
// ---------------------------------------------------------------------------
__global__ __launch_bounds__(256)
void flash_attn_f32(const float* __restrict__ qkv, float* __restrict__ attn_out) {
  const int qt = blockIdx.x, h = blockIdx.y, b = blockIdx.z;
  const int t  = threadIdx.x;
  const int tx = t & 15, ty = t >> 4;

  __shared__ float Qs[64][68];   // [q][d]   (row stride 68: 16B-aligned, 2-way reads)
  __shared__ float Kt[64][65];   // [d][kk]  (transposed; pad 65 -> conflict-free-ish)
  __shared__ float Vs[64][64];   // [kk][dh]
  __shared__ float Ps[64][68];   // [q][kk]  (probabilities)

  const size_t rs = (size_t)(3 * D_);
  const float* base = qkv + (size_t)b * S_ * rs + (size_t)h * DH_;

  // Load + scale Q tile (64 x 64), 1024 float4 total, 4 per thread
  {
    const float* qb = base + (size_t)(qt * 64) * rs;
#pragma unroll
    for (int i = 0; i < 4; i++) {
      int s = t + i * 256;
      int row = s >> 4, c4 = s & 15;
      float4 v = *reinterpret_cast<const float4*>(qb + (size_t)row * rs + c4 * 4);
      v.x *= 0.125f; v.y *= 0.125f; v.z *= 0.125f; v.w *= 0.125f;
      *reinterpret_cast<float4*>(&Qs[row][c4 * 4]) = v;
    }
  }

  float o[4][4];
  float mrow[4], lrow[4];
#pragma unroll
  for (int i = 0; i < 4; i++) {
    mrow[i] = -1e30f;
    lrow[i] = 0.f;
#pragma unroll
    for (int j = 0; j < 4; j++) o[i][j] = 0.f;
  }

  const float* kb = base + D_;
  const float* vb = base + 2 * D_;

  for (int kv0 = 0; kv0 < S_; kv0 += 64) {
    __syncthreads();   // prev iter done reading Kt/Vs/Ps; Q visible after 1st
    // Load K (transposed) and V tiles
#pragma unroll
    for (int i = 0; i < 4; i++) {
      int s = t + i * 256;
      int row = s >> 4, c4 = s & 15;
      float4 kv4 = *reinterpret_cast<const float4*>(kb + (size_t)(kv0 + row) * rs + c4 * 4);
      Kt[c4 * 4 + 0][row] = kv4.x;
      Kt[c4 * 4 + 1][row] = kv4.y;
      Kt[c4 * 4 + 2][row] = kv4.z;
      Kt[c4 * 4 + 3][row] = kv4.w;
      *reinterpret_cast<float4*>(&Vs[row][c4 * 4]) =
          *reinterpret_cast<const float4*>(vb + (size_t)(kv0 + row) * rs + c4 * 4);
    }
    __syncthreads();

    // Scores: sc[i][j] = sum_d Qs[ty*4+i][d] * Kt[d][tx*4+j]  (already /8 via Q)
    float sc[4][4];
#pragma unroll
    for (int i = 0; i < 4; i++)
#pragma unroll
      for (int j = 0; j < 4; j++) sc[i][j] = 0.f;

#pragma unroll 8
    for (int d = 0; d < 64; d++) {
      float a[4], bb[4];
#pragma unroll
      for (int i = 0; i < 4; i++) a[i] = Qs[ty * 4 + i][d];
#pragma unroll
      for (int j = 0; j < 4; j++) bb[j] = Kt[d][tx * 4 + j];
#pragma unroll
      for (int i = 0; i < 4; i++)
#pragma unroll
        for (int j = 0; j < 4; j++)
          sc[i][j] = fmaf(a[i], bb[j], sc[i][j]);
    }

    // Online softmax update (per q-row; 16 lanes per row, in-wave)
    float p[4][4];
#pragma unroll
    for (int i = 0; i < 4; i++) {
      float rm = fmaxf(fmaxf(sc[i][0], sc[i][1]), fmaxf(sc[i][2], sc[i][3]));
      rm = fmaxf(rm, __shfl_xor(rm, 1, 16));
      rm = fmaxf(rm, __shfl_xor(rm, 2, 16));
      rm = fmaxf(rm, __shfl_xor(rm, 4, 16));
      rm = fmaxf(rm, __shfl_xor(rm, 8, 16));
      float mnew  = fmaxf(mrow[i], rm);
      float alpha = __expf(mrow[i] - mnew);
      float rsum  = 0.f;
#pragma unroll
      for (int j = 0; j < 4; j++) {
        p[i][j] = __expf(sc[i][j] - mnew);
        rsum += p[i][j];
      }
      rsum += __shfl_xor(rsum, 1, 16);
      rsum += __shfl_xor(rsum, 2, 16);
      rsum += __shfl_xor(rsum, 4, 16);
      rsum += __shfl_xor(rsum, 8, 16);
      lrow[i] = lrow[i] * alpha + rsum;
      mrow[i] = mnew;
#pragma unroll
      for (int j = 0; j < 4; j++) o[i][j] *= alpha;
    }

    // Publish P tile
#pragma unroll
    for (int i = 0; i < 4; i++) {
      float4 v = make_float4(p[i][0], p[i][1], p[i][2], p[i][3]);
      *reinterpret_cast<float4*>(&Ps[ty * 4 + i][tx * 4]) = v;
    }
    __syncthreads();

    // PV: o[i][j] += sum_kk Ps[ty*4+i][kk] * Vs[kk][tx*4+j]
#pragma unroll 8
    for (int kk = 0; kk < 64; kk++) {
      float a[4], bb[4];
#pragma unroll
      for (int i = 0; i < 4; i++) a[i] = Ps[ty * 4 + i][kk];
#pragma unroll
      for (int j = 0; j < 4; j++) bb[j] = Vs[kk][tx * 4 + j];
#pragma unroll
      for (int i = 0; i < 4; i++)
#pragma unroll
        for (int j = 0; j < 4; j++)
          o[i][j] = fmaf(a[i], bb[j], o[i][j]);
    }
  }

  // Epilogue: normalize and write attn_out [B*S, D] at col h*64
  float* obase = attn_out + ((size_t)b * S_ + (size_t)qt * 64) * D_ + (size_t)h * DH_;
#pragma unroll
  for (int i = 0; i < 4; i++) {
    float inv = 1.f / lrow[i];
    float4 v = make_float4(o[i][0] * inv, o[i][1] * inv, o[i][2] * inv, o[i][3] * inv);
    *reinterpret_cast<float4*>(obase + (size_t)(ty * 4 + i) * D_ + tx * 4) = v;
  }
}

// ---------------------------------------------------------------------------
extern "C" void kernel_launch(void* const* d_in, const int* in_sizes, int n_in,
                              void* d_out, int out_size, void* d_ws, size_t ws_size,
                              hipStream_t stream) {
  const float* x     = (const float*)d_in[0];
  const float* W_qkv = (const float*)d_in[1];
  const float* b_qkv = (const float*)d_in[2];
  const float* W_out = (const float*)d_in[3];
  const float* b_out = (const float*)d_in[4];
  float* out = (float*)d_out;

  float* qkv  = (float*)d_ws;                       // [4096, 3072] = 48 MiB
  float* attn = qkv + (size_t)M_ * (3 * D_);        // [4096, 1024] = 16 MiB

  // 1) QKV projection: [4096,1024] @ [1024,3072] + b_qkv
  gemm_bias_f32<<<dim3(3 * D_ / 128, M_ / 128), 256, 0, stream>>>(
      x, W_qkv, b_qkv, qkv, M_, 3 * D_, D_);

  // 2) Flash attention per (b, h, q-tile)
  flash_attn_f32<<<dim3(S_ / 64, H_, B_), 256, 0, stream>>>(qkv, attn);

  // 3) Output projection: [4096,1024] @ [1024,1024] + b_out
  gemm_bias_f32<<<dim3(D_ / 128, M_ / 128), 256, 0, stream>>>(
      attn, W_out, b_out, out, M_, D_, D_);
}

// Round 2
// 151.461 us; speedup vs baseline: 6.4060x; 6.4060x over previous
//
#include <hip/hip_runtime.h>

typedef _Float16 half8  __attribute__((ext_vector_type(8)));
typedef _Float16 half4  __attribute__((ext_vector_type(4)));
typedef float    floatx4  __attribute__((ext_vector_type(4)));
typedef float    floatx16 __attribute__((ext_vector_type(16)));

constexpr int B_ = 2, S_ = 2048, D_ = 1024, H_ = 16, M_ = 4096;
constexpr float QSCALE = 0.18033688011112042f;  // log2(e)/8

__device__ __forceinline__ void gload16(const void* g, void* l) {
  __builtin_amdgcn_global_load_lds((const __attribute__((address_space(1))) void*)g,
                                   (__attribute__((address_space(3))) void*)l, 16, 0, 0);
}

// ---------------------------------------------------------------------------
// cast fp32 -> fp16, 8 elems/thread
// ---------------------------------------------------------------------------
__global__ __launch_bounds__(256) void cast_f32_f16(const float* __restrict__ in,
                                                    _Float16* __restrict__ out, int n8) {
  int i = blockIdx.x * 256 + threadIdx.x;
  if (i >= n8) return;
  float4 a = reinterpret_cast<const float4*>(in)[2 * i];
  float4 b = reinterpret_cast<const float4*>(in)[2 * i + 1];
  half8 h;
  h[0] = (_Float16)a.x; h[1] = (_Float16)a.y; h[2] = (_Float16)a.z; h[3] = (_Float16)a.w;
  h[4] = (_Float16)b.x; h[5] = (_Float16)b.y; h[6] = (_Float16)b.z; h[7] = (_Float16)b.w;
  reinterpret_cast<half8*>(out)[i] = h;
}

// ---------------------------------------------------------------------------
// W[K][N] fp32 -> WT[N][K] fp16 (64x64 tiles)
// ---------------------------------------------------------------------------
__global__ __launch_bounds__(256) void transpose_cast(const float* __restrict__ W,
                                                      _Float16* __restrict__ WT,
                                                      int K, int N) {
  __shared__ float Ws[64][65];
  const int n0 = blockIdx.x * 64, k0 = blockIdx.y * 64;
  const int t = threadIdx.x;
#pragma unroll
  for (int i = 0; i < 4; i++) {
    int idx = t + 256 * i;
    int r = idx >> 4, c4 = idx & 15;
    float4 v = *reinterpret_cast<const float4*>(W + (size_t)(k0 + r) * N + n0 + c4 * 4);
    Ws[r][c4 * 4 + 0] = v.x; Ws[r][c4 * 4 + 1] = v.y;
    Ws[r][c4 * 4 + 2] = v.z; Ws[r][c4 * 4 + 3] = v.w;
  }
  __syncthreads();
#pragma unroll
  for (int i = 0; i < 2; i++) {
    int idx = t + 256 * i;
    int r = idx >> 3, ck = idx & 7;   // out row n = r, k chunk ck
    half8 h;
#pragma unroll
    for (int j = 0; j < 8; j++) h[j] = (_Float16)Ws[ck * 8 + j][r];
    *reinterpret_cast<half8*>(WT + (size_t)(n0 + r) * K + k0 + ck * 8) = h;
  }
}

// ---------------------------------------------------------------------------
// fp16 MFMA GEMM: C[M][N] = A[M][K] @ BT[N][K]^T + bias
// 128x128 tile, BK=64, 4 waves, 16x16x32 f16, XOR-swizzled LDS.
// OUT_HALF: fp16 out with per-col scale (cols < ncut get scale_lo); else fp32.
// ---------------------------------------------------------------------------
template <bool OUT_HALF>
__global__ __launch_bounds__(256) void gemm_mfma(const _Float16* __restrict__ A,
                                                 const _Float16* __restrict__ BT,
                                                 const float* __restrict__ bias,
                                                 void* __restrict__ Cout,
                                                 int M, int N, int K,
                                                 float scale_lo, int ncut) {
  __shared__ _Float16 As[128 * 64];
  __shared__ _Float16 Bs[128 * 64];
  const int t = threadIdx.x, w = t >> 6, lane = t & 63;
  const int m0 = blockIdx.y * 128, n0 = blockIdx.x * 128;
  const int wr = (w >> 1) * 64, wc = (w & 1) * 64;

  floatx4 acc[4][4] = {};

  for (int k0 = 0; k0 < K; k0 += 64) {
    __syncthreads();
#pragma unroll
    for (int i = 0; i < 4; i++) {
      int idx = t + 256 * i;
      int r = idx >> 3, c = idx & 7;
      int cs = c ^ (r & 7);
      gload16(A + (size_t)(m0 + r) * K + k0 + cs * 8, (char*)As + idx * 16);
      gload16(BT + (size_t)(n0 + r) * K + k0 + cs * 8, (char*)Bs + idx * 16);
    }
    __syncthreads();
#pragma unroll
    for (int ks = 0; ks < 2; ks++) {
      half8 af[4], bf[4];
#pragma unroll
      for (int r = 0; r < 4; r++) {
        int row = wr + r * 16 + (lane & 15);
        int ch = (ks * 4 + (lane >> 4)) ^ (row & 7);
        af[r] = *reinterpret_cast<const half8*>((const char*)As + row * 128 + ch * 16);
      }
#pragma unroll
      for (int c = 0; c < 4; c++) {
        int row = wc + c * 16 + (lane & 15);
        int ch = (ks * 4 + (lane >> 4)) ^ (row & 7);
        bf[c] = *reinterpret_cast<const half8*>((const char*)Bs + row * 128 + ch * 16);
      }
#pragma unroll
      for (int r = 0; r < 4; r++)
#pragma unroll
        for (int c = 0; c < 4; c++)
          acc[r][c] = __builtin_amdgcn_mfma_f32_16x16x32_f16(af[r], bf[c], acc[r][c], 0, 0, 0);
    }
  }

#pragma unroll
  for (int r = 0; r < 4; r++)
#pragma unroll
    for (int c = 0; c < 4; c++) {
      int col = n0 + wc + c * 16 + (lane & 15);
      float bv = bias[col];
      float sc = (col < ncut) ? scale_lo : 1.0f;
#pragma unroll
      for (int reg = 0; reg < 4; reg++) {
        int row = m0 + wr + r * 16 + (lane >> 4) * 4 + reg;
        float v = (acc[r][c][reg] + bv) * sc;
        if (OUT_HALF)
          reinterpret_cast<_Float16*>(Cout)[(size_t)row * N + col] = (_Float16)v;
        else
          reinterpret_cast<float*>(Cout)[(size_t)row * N + col] = v;
      }
    }
}

// ---------------------------------------------------------------------------
// V transpose: qkv[B*S][3D] fp16 (V slice) -> Vt[(b*H+h)*64 + d][S] fp16
// ---------------------------------------------------------------------------
__global__ __launch_bounds__(256) void v_transpose(const _Float16* __restrict__ qkv,
                                                   _Float16* __restrict__ Vt) {
  __shared__ _Float16 Vs[64][72];
  const int s0 = blockIdx.x * 64, bh = blockIdx.y;
  const int b = bh >> 4, h = bh & 15;
  const int t = threadIdx.x;
#pragma unroll
  for (int i = 0; i < 2; i++) {
    int idx = t + 256 * i;
    int r = idx >> 3, c = idx & 7;
    half8 v = *reinterpret_cast<const half8*>(
        qkv + (size_t)(b * S_ + s0 + r) * (3 * D_) + 2 * D_ + h * 64 + c * 8);
    *reinterpret_cast<half8*>(&Vs[r][c * 8]) = v;
  }
  __syncthreads();
#pragma unroll
  for (int i = 0; i < 2; i++) {
    int idx = t + 256 * i;
    int d = idx >> 3, c = idx & 7;
    half8 o;
#pragma unroll
    for (int j = 0; j < 8; j++) o[j] = Vs[c * 8 + j][d];
    *reinterpret_cast<half8*>(Vt + ((size_t)bh * 64 + d) * S_ + s0 + c * 8) = o;
  }
}

// ---------------------------------------------------------------------------
// Flash attention, fp16 MFMA 32x32x16.
// Block: 256 thr = 4 waves; Q-tile 128 rows (32/wave); KV-tile 64.
// Swapped QK^T (S^T = K @ Q^T) and swapped PV (O^T = V^T @ P^T):
// q is lane-local (q = lane&31) for softmax state AND the O accumulator.
// Q pre-scaled by log2(e)/8 in GEMM1 epilogue -> softmax in exp2 domain.
// ---------------------------------------------------------------------------
__global__ __launch_bounds__(256) void flash_mfma(const _Float16* __restrict__ qkv,
                                                  const _Float16* __restrict__ Vt,
                                                  _Float16* __restrict__ attn_out) {
  const int qt = blockIdx.x, h = blockIdx.y, b = blockIdx.z;
  const int t = threadIdx.x, w = t >> 6, lane = t & 63;
  const int lo = lane & 31, hi = lane >> 5;

  __shared__ _Float16 Ks[64 * 64];    // [kk][d], 128B rows, chunk^(row&7)
  __shared__ _Float16 Vts[64 * 64];   // [d][kk], same swizzle
  __shared__ _Float16 Ps[4 * 2048];   // per-wave [q=32][kk=64], same swizzle

  // Q fragments (B operand; col=q=lo, k=d): 4 k-steps of 16
  const int qrow = qt * 128 + w * 32 + lo;
  const _Float16* qbase = qkv + (size_t)(b * S_ + qrow) * (3 * D_) + h * 64;
  half8 qf[4];
#pragma unroll
  for (int kd = 0; kd < 4; kd++)
    qf[kd] = *reinterpret_cast<const half8*>(qbase + kd * 16 + hi * 8);

  floatx16 s0, s1, o0, o1;
#pragma unroll
  for (int r = 0; r < 16; r++) { o0[r] = 0.f; o1[r] = 0.f; }
  float m = -1e30f, l = 0.f;

  const size_t kbase = (size_t)(b * S_) * (3 * D_) + D_ + h * 64;
  const size_t vbase = (size_t)(b * H_ + h) * 64 * S_;

  for (int kv0 = 0; kv0 < S_; kv0 += 64) {
    __syncthreads();
#pragma unroll
    for (int i = 0; i < 2; i++) {
      int idx = t + 256 * i;
      int r = idx >> 3, c = idx & 7, cs = c ^ (r & 7);
      gload16(qkv + kbase + (size_t)(kv0 + r) * (3 * D_) + cs * 8, (char*)Ks + idx * 16);
      gload16(Vt + vbase + (size_t)r * S_ + kv0 + cs * 8, (char*)Vts + idx * 16);
    }
    __syncthreads();

    // S^T = K @ Q^T : lane holds col q=lo, rows kk=(reg&3)+8*(reg>>2)+4*hi (+32 for s1)
#pragma unroll
    for (int r = 0; r < 16; r++) { s0[r] = 0.f; s1[r] = 0.f; }
#pragma unroll
    for (int kd = 0; kd < 4; kd++) {
      int r0 = lo, r1 = 32 + lo;
      int ch = kd * 2 + hi;
      half8 k0f = *reinterpret_cast<const half8*>((const char*)Ks + r0 * 128 + ((ch ^ (r0 & 7)) * 16));
      half8 k1f = *reinterpret_cast<const half8*>((const char*)Ks + r1 * 128 + ((ch ^ (r1 & 7)) * 16));
      s0 = __builtin_amdgcn_mfma_f32_32x32x16_f16(k0f, qf[kd], s0, 0, 0, 0);
      s1 = __builtin_amdgcn_mfma_f32_32x32x16_f16(k1f, qf[kd], s1, 0, 0, 0);
    }

    // online softmax, exp2 domain; q = lo is lane-local
    float pm = -1e30f;
#pragma unroll
    for (int r = 0; r < 16; r++) pm = fmaxf(pm, fmaxf(s0[r], s1[r]));
    pm = fmaxf(pm, __shfl_xor(pm, 32));
    float mn = fmaxf(m, pm);
    float alpha = __builtin_amdgcn_exp2f(m - mn);
    m = mn;
    float rs = 0.f;
#pragma unroll
    for (int r = 0; r < 16; r++) {
      s0[r] = __builtin_amdgcn_exp2f(s0[r] - mn);
      s1[r] = __builtin_amdgcn_exp2f(s1[r] - mn);
      rs += s0[r] + s1[r];
    }
    rs += __shfl_xor(rs, 32);
    l = l * alpha + rs;
#pragma unroll
    for (int r = 0; r < 16; r++) { o0[r] *= alpha; o1[r] *= alpha; }

    // write P (fp16) to per-wave LDS: row q=lo, kk = 32*mt+8*rq+4*hi+{0..3}
#pragma unroll
    for (int mt = 0; mt < 2; mt++)
#pragma unroll
      for (int rq = 0; rq < 4; rq++) {
        half4 pv;
#pragma unroll
        for (int e = 0; e < 4; e++) pv[e] = (_Float16)((mt ? s1 : s0)[4 * rq + e]);
        int ch = (4 * mt + rq) ^ (lo & 7);
        *reinterpret_cast<half4*>((char*)Ps + w * 4096 + lo * 128 + ch * 16 + hi * 8) = pv;
      }

    // O^T += V^T @ P^T : A = V^T (row=d), B = P (col=q)
#pragma unroll
    for (int ks = 0; ks < 4; ks++) {
      int ch = ks * 2 + hi;
      half8 pf = *reinterpret_cast<const half8*>(
          (const char*)Ps + w * 4096 + lo * 128 + ((ch ^ (lo & 7)) * 16));
      int r0 = lo, r1 = 32 + lo;
      half8 vf0 = *reinterpret_cast<const half8*>((const char*)Vts + r0 * 128 + ((ch ^ (r0 & 7)) * 16));
      half8 vf1 = *reinterpret_cast<const half8*>((const char*)Vts + r1 * 128 + ((ch ^ (r1 & 7)) * 16));
      o0 = __builtin_amdgcn_mfma_f32_32x32x16_f16(vf0, pf, o0, 0, 0, 0);
      o1 = __builtin_amdgcn_mfma_f32_32x32x16_f16(vf1, pf, o1, 0, 0, 0);
    }
  }

  // epilogue: lane holds O^T[d][q=lo]; d = 32*mt + 8*rq + 4*hi + e
  float inv = 1.0f / l;
  _Float16* ob = attn_out + (size_t)(b * S_ + qt * 128 + w * 32 + lo) * D_ + h * 64;
#pragma unroll
  for (int mt = 0; mt < 2; mt++)
#pragma unroll
    for (int rq = 0; rq < 4; rq++) {
      half4 v;
#pragma unroll
      for (int e = 0; e < 4; e++) v[e] = (_Float16)((mt ? o1 : o0)[4 * rq + e] * inv);
      *reinterpret_cast<half4*>(ob + 32 * mt + 8 * rq + 4 * hi) = v;
    }
}

// ---------------------------------------------------------------------------
extern "C" void kernel_launch(void* const* d_in, const int* in_sizes, int n_in,
                              void* d_out, int out_size, void* d_ws, size_t ws_size,
                              hipStream_t stream) {
  const float* x     = (const float*)d_in[0];
  const float* W_qkv = (const float*)d_in[1];
  const float* b_qkv = (const float*)d_in[2];
  const float* W_out = (const float*)d_in[3];
  const float* b_out = (const float*)d_in[4];
  float* out = (float*)d_out;

  _Float16* xh   = (_Float16*)d_ws;                 // 4M halves  (8 MB)
  _Float16* WqT  = xh   + (size_t)M_ * D_;          // 3M         (6 MB)
  _Float16* WoT  = WqT  + (size_t)3 * D_ * D_;      // 1M         (2 MB)
  _Float16* qkvh = WoT  + (size_t)D_ * D_;          // 12M        (24 MB)
  _Float16* Vth  = qkvh + (size_t)M_ * 3 * D_;      // 4M         (8 MB)
  _Float16* atth = Vth  + (size_t)B_ * H_ * 64 * S_; // 4M        (8 MB)

  // 1) casts / transposes
  cast_f32_f16<<<(M_ * D_ / 8 + 255) / 256, 256, 0, stream>>>(x, xh, M_ * D_ / 8);
  transpose_cast<<<dim3(3 * D_ / 64, D_ / 64), 256, 0, stream>>>(W_qkv, WqT, D_, 3 * D_);
  transpose_cast<<<dim3(D_ / 64, D_ / 64), 256, 0, stream>>>(W_out, WoT, D_, D_);

  // 2) QKV GEMM (fp16 out; Q columns pre-scaled by log2e/8)
  gemm_mfma<true><<<dim3(3 * D_ / 128, M_ / 128), 256, 0, stream>>>(
      xh, WqT, b_qkv, qkvh, M_, 3 * D_, D_, QSCALE, D_);

  // 3) V transpose
  v_transpose<<<dim3(S_ / 64, B_ * H_), 256, 0, stream>>>(qkvh, Vth);

  // 4) flash attention
  flash_mfma<<<dim3(S_ / 128, H_, B_), 256, 0, stream>>>(qkvh, Vth, atth);

  // 5) output projection (fp32 out)
  gemm_mfma<false><<<dim3(D_ / 128, M_ / 128), 256, 0, stream>>>(
      atth, WoT, b_out, out, M_, D_, D_, 1.0f, 0);
}